// Round 8
// baseline (260.462 us; speedup 1.0000x reference)
//
#include <hip/hip_runtime.h>

// TensorTree, FUSED single kernel. out[b,u] = sum_c W[b,c]*T[u,c],
// W[b,c] = w1[b,c&15]*w2[b,c>>4]; T built per-block in LDS (no d_ws, no
// cross-kernel dependency — round 7's post-timing failure was eval reading
// stale T through the d_ws handoff under graph replay; this removes it).
// GEMM on f16 MFMA with scaled hi/lo split (verified round 7, first-call
// absmax 0.0625): Wh=f16(W), Wl=f16(2048*(W-Wh)), same for T;
// acc_hi += Wh*Th; acc_lo += Wh*Tl + Wl*Th; out = acc_hi + acc_lo/2048.
// Layouts (verified): A[m=lane&15][k=quad*8+j], B[k=quad*8+j][n=lane&15],
// D[row=quad*4+reg][col=lane&15].
// Block: 256 threads (4 waves), 256 batches; grid 256 = 1 block/CU.
// LDS: T hi/lo 32 KB + 40 KB scratch (build phases, then per-wave W tiles).

#define BB 65536
#define FF 8
#define RR 10
#define UU 32
#define LO_SCALE 2048.0f
#define LO_INV   (1.0f / 2048.0f)

typedef _Float16 half8 __attribute__((ext_vector_type(8)));
typedef float floatx4 __attribute__((ext_vector_type(4)));

__global__ __launch_bounds__(256) void tensortree_fused(
    const float* __restrict__ X,
    const float* __restrict__ core11, const float* __restrict__ core12,
    const float* __restrict__ core13, const float* __restrict__ core14,
    const float* __restrict__ core21, const float* __restrict__ core22,
    const float* __restrict__ FM, const float* __restrict__ MT,
    float* __restrict__ out)
{
    const int tid = threadIdx.x;

    __shared__ __attribute__((aligned(16))) _Float16 sTh[UU * 256];  // 16 KB
    __shared__ __attribute__((aligned(16))) _Float16 sTl[UU * 256];  // 16 KB
    __shared__ __attribute__((aligned(16))) char scratch[40960];     // 40 KB

    float* sFM = (float*)scratch;             // 2560 f32: FM slice; later sR1
    float* sP  = (float*)(scratch + 10240);   // 2560 f32: level-1 results
    float* sQ  = (float*)(scratch + 20480);   // 5120 f32: level-2 results
    float* sR1 = sFM;                         // alias (sFM dead after phase A)

    // ================= T build: 2 groups of 16 units =================
    for (int G = 0; G < 2; ++G) {
        const int ubase = G * 16;

        // L: stage FM slice. sFM[((a*10+r)*8+f)*16 + u']
        for (int t = tid; t < 2560; t += 256) {
            const int up   = t & 15;
            const int rest = t >> 4;          // (a*10+r)*8+f, 0..159
            sFM[t] = FM[rest * 32 + ubase + up];
        }
        __syncthreads();

        // A: level-1 pairs. task -> (j, u', P, s); 100-FMA contraction.
        for (int t = tid; t < 2560; t += 256) {
            const int j    = t % 10;
            const int rest = t / 10;          // 0..255
            const int up   = rest & 15;
            const int r2   = rest >> 4;       // 0..15
            const int P    = r2 & 3;
            const int s    = r2 >> 2;         // a_lo + 2*a_hi
            const int ai = s & 1, bi = s >> 1;
            const int fa = 2 * P, fb = 2 * P + 1;
            const float* cp = (P == 0) ? core11 : (P == 1) ? core12
                            : (P == 2) ? core13 : core14;
            float a[RR], b[RR];
#pragma unroll
            for (int i = 0; i < RR; ++i) {
                a[i] = sFM[((ai * RR + i) * FF + fa) * 16 + up];
                b[i] = sFM[((bi * RR + i) * FF + fb) * 16 + up];
            }
            float acc = 0.0f;
#pragma unroll
            for (int i = 0; i < RR; ++i)
#pragma unroll
                for (int k = 0; k < RR; ++k)
                    acc = fmaf(a[i] * b[k], cp[(i * RR + k) * RR + j], acc);
            sP[((up * 4 + P) * 4 + s) * 10 + j] = acc;
        }
        __syncthreads();

        // B: level-2. task -> (j, u', side, combo).
        for (int t = tid; t < 5120; t += 256) {
            const int j    = t % 10;
            const int rest = t / 10;          // 0..511
            const int up   = rest & 15;
            const int r2   = rest >> 4;       // 0..31
            const int side  = r2 >> 4;
            const int combo = r2 & 15;
            const float* cp = side ? core22 : core21;
            float a[RR], b[RR];
#pragma unroll
            for (int i = 0; i < RR; ++i) {
                a[i] = sP[((up * 4 + side * 2 + 0) * 4 + (combo & 3)) * 10 + i];
                b[i] = sP[((up * 4 + side * 2 + 1) * 4 + (combo >> 2)) * 10 + i];
            }
            float acc = 0.0f;
#pragma unroll
            for (int i = 0; i < RR; ++i)
#pragma unroll
                for (int k = 0; k < RR; ++k)
                    acc = fmaf(a[i] * b[k], cp[(i * RR + k) * RR + j], acc);
            sQ[((up * 2 + side) * 16 + combo) * 10 + j] = acc;
        }
        __syncthreads();

        // C: R1[p][j] = sum_i Q1[p][i]*MT[i][j]   (sR1 aliases sFM, dead)
        for (int t = tid; t < 2560; t += 256) {
            const int j    = t % 10;
            const int rest = t / 10;
            const int up   = rest & 15;
            const int p    = rest >> 4;
            float acc = 0.0f;
#pragma unroll
            for (int i = 0; i < RR; ++i)
                acc = fmaf(sQ[((up * 2 + 0) * 16 + p) * 10 + i], MT[i * RR + j], acc);
            sR1[(up * 16 + p) * 10 + j] = acc;
        }
        __syncthreads();

        // D: T[u][q*16+p] = sum_j R1[p][j]*Q2[q][j]; f16 hi + scaled lo.
        for (int t = tid; t < 4096; t += 256) {
            const int c  = t & 255;
            const int up = t >> 8;
            const int p = c & 15, q = c >> 4;
            float acc = 0.0f;
#pragma unroll
            for (int j = 0; j < RR; ++j)
                acc = fmaf(sR1[(up * 16 + p) * 10 + j],
                           sQ[((up * 2 + 1) * 16 + q) * 10 + j], acc);
            const _Float16 h = (_Float16)acc;
            sTh[(ubase + up) * 256 + c] = h;
            sTl[(ubase + up) * 256 + c] = (_Float16)(LO_SCALE * (acc - (float)h));
        }
        __syncthreads();
    }

    // ================= GEMM phase (per wave, r7-verified math) ==========
    const int wv   = tid >> 6;
    const int lane = tid & 63;
    const int quad = lane >> 4;
    const int l15  = lane & 15;
    const int bbase = blockIdx.x * 256 + wv * 64;
    const int b     = bbase + lane;

    // per-wave private W tiles (alias build scratch; barrier above separates)
    _Float16* Whp = (_Float16*)(scratch + wv * 10240);          // 64 x 40 halves
    _Float16* Wlp = (_Float16*)(scratch + wv * 10240 + 5120);

    // X[b,:] and w1/w2
    float x0[2], x1[2], x2[2], x3[2], x4[2], x5[2], x6[2], x7[2];
    {
        const float4* xp = reinterpret_cast<const float4*>(X + (size_t)b * 16);
        float4 v0 = xp[0], v1 = xp[1], v2 = xp[2], v3 = xp[3];
        x0[0]=v0.x; x0[1]=v0.y; x1[0]=v0.z; x1[1]=v0.w;
        x2[0]=v1.x; x2[1]=v1.y; x3[0]=v1.z; x3[1]=v1.w;
        x4[0]=v2.x; x4[1]=v2.y; x5[0]=v2.z; x5[1]=v2.w;
        x6[0]=v3.x; x6[1]=v3.y; x7[0]=v3.z; x7[1]=v3.w;
    }
    float t01[4], t23[4], t45[4], t67[4];
#pragma unroll
    for (int a1 = 0; a1 < 2; ++a1)
#pragma unroll
        for (int a0 = 0; a0 < 2; ++a0) {
            t01[a1*2+a0] = x0[a0] * x1[a1];
            t23[a1*2+a0] = x2[a0] * x3[a1];
            t45[a1*2+a0] = x4[a0] * x5[a1];
            t67[a1*2+a0] = x6[a0] * x7[a1];
        }
    float w1f[16], w2f[16];
#pragma unroll
    for (int p = 0; p < 16; ++p) {
        w1f[p] = t01[p & 3] * t23[p >> 2];
        w2f[p] = t45[p & 3] * t67[p >> 2];
    }

    // B-frag preload from LDS T: u = nt*16+l15, k = cc*32 + quad*8 + j
    half8 Bh[2][8], Bl[2][8];
#pragma unroll
    for (int nt = 0; nt < 2; ++nt)
#pragma unroll
        for (int cc = 0; cc < 8; ++cc) {
            const int off = (nt * 16 + l15) * 256 + cc * 32 + quad * 8;
            Bh[nt][cc] = *reinterpret_cast<const half8*>(sTh + off);
            Bl[nt][cc] = *reinterpret_cast<const half8*>(sTl + off);
        }

    floatx4 acch[4][2], accl[4][2];
#pragma unroll
    for (int mt = 0; mt < 4; ++mt)
#pragma unroll
        for (int nt = 0; nt < 2; ++nt) {
            acch[mt][nt] = (floatx4){0.f, 0.f, 0.f, 0.f};
            accl[mt][nt] = (floatx4){0.f, 0.f, 0.f, 0.f};
        }

    // 8 k-chunks of 32; W tile is wave-private -> no barriers in this loop.
#pragma unroll 2
    for (int cc = 0; cc < 8; ++cc) {
        // build + store W chunk: c = cc*32 + g*8 + j -> p=(g&1)*8+j, q=cc*2+(g>>1)
#pragma unroll
        for (int g = 0; g < 4; ++g) {
            const float wq = w2f[cc * 2 + (g >> 1)];
            half8 vh, vl;
#pragma unroll
            for (int j = 0; j < 8; ++j) {
                const float w = w1f[(g & 1) * 8 + j] * wq;
                const _Float16 h = (_Float16)w;
                vh[j] = h;
                vl[j] = (_Float16)(LO_SCALE * (w - (float)h));
            }
            *reinterpret_cast<half8*>(&Whp[lane * 40 + g * 8]) = vh;
            *reinterpret_cast<half8*>(&Wlp[lane * 40 + g * 8]) = vl;
        }

        // A-frags + MFMAs
#pragma unroll
        for (int mt = 0; mt < 4; ++mt) {
            const int row = mt * 16 + l15;
            half8 ah = *reinterpret_cast<const half8*>(&Whp[row * 40 + quad * 8]);
            half8 al = *reinterpret_cast<const half8*>(&Wlp[row * 40 + quad * 8]);
#pragma unroll
            for (int nt = 0; nt < 2; ++nt) {
                acch[mt][nt] = __builtin_amdgcn_mfma_f32_16x16x32_f16(
                    ah, Bh[nt][cc], acch[mt][nt], 0, 0, 0);
                accl[mt][nt] = __builtin_amdgcn_mfma_f32_16x16x32_f16(
                    ah, Bl[nt][cc], accl[mt][nt], 0, 0, 0);
                accl[mt][nt] = __builtin_amdgcn_mfma_f32_16x16x32_f16(
                    al, Bh[nt][cc], accl[mt][nt], 0, 0, 0);
            }
        }
    }

    // epilogue: D[row=quad*4+r][col=l15]; out = acc_hi + acc_lo/2048
#pragma unroll
    for (int mt = 0; mt < 4; ++mt)
#pragma unroll
        for (int nt = 0; nt < 2; ++nt)
#pragma unroll
            for (int r = 0; r < 4; ++r) {
                const int brow = bbase + mt * 16 + quad * 4 + r;
                out[(size_t)brow * UU + nt * 16 + l15] =
                    acch[mt][nt][r] + accl[mt][nt][r] * LO_INV;
            }
}

extern "C" void kernel_launch(void* const* d_in, const int* in_sizes, int n_in,
                              void* d_out, int out_size, void* d_ws, size_t ws_size,
                              hipStream_t stream) {
    const float* X      = (const float*)d_in[0];
    const float* core11 = (const float*)d_in[1];
    const float* core12 = (const float*)d_in[2];
    const float* core13 = (const float*)d_in[3];
    const float* core14 = (const float*)d_in[4];
    const float* core21 = (const float*)d_in[5];
    const float* core22 = (const float*)d_in[6];
    const float* FM     = (const float*)d_in[7];
    const float* MT     = (const float*)d_in[8];
    float* out          = (float*)d_out;

    tensortree_fused<<<dim3(BB / 256), dim3(256), 0, stream>>>(
        X, core11, core12, core13, core14, core21, core22, FM, MT, out);
}